// Round 6
// baseline (1345.206 us; speedup 1.0000x reference)
//
#include <hip/hip_runtime.h>

// MUL=128, Z=10, L_DIMS=(1,3,5,7) offs (0,1,4,9), MM_DIMS=(1,3)

__device__ __forceinline__ float silu_f(float x) {
  return x / (1.0f + __expf(-x));
}

__global__ void k_zero_int(int* p, int n) {
  int i = blockIdx.x * blockDim.x + threadIdx.x;
  if (i < n) p[i] = 0;
}

// Mc = M1@M2@M3@M4 / 2048  (linear MLP collapse), Mc is [16,256]
__global__ __launch_bounds__(256) void k_prep(
    const float* __restrict__ M1, const float* __restrict__ M2,
    const float* __restrict__ M3, const float* __restrict__ M4,
    float* __restrict__ Mc) {
  __shared__ float T1[16 * 64];
  __shared__ float T2[16 * 64];
  int t = threadIdx.x;
  for (int i = t; i < 16 * 64; i += 256) {
    int r = i >> 6, c = i & 63;
    float s = 0.f;
    for (int k = 0; k < 64; k++) s += M1[r * 64 + k] * M2[k * 64 + c];
    T1[i] = s;
  }
  __syncthreads();
  for (int i = t; i < 16 * 64; i += 256) {
    int r = i >> 6, c = i & 63;
    float s = 0.f;
    for (int k = 0; k < 64; k++) s += T1[r * 64 + k] * M3[k * 64 + c];
    T2[i] = s;
  }
  __syncthreads();
  for (int i = t; i < 16 * 256; i += 256) {
    int r = i >> 8, c = i & 255;
    float s = 0.f;
    for (int k = 0; k < 64; k++) s += T2[r * 64 + k] * M4[k * 256 + c];
    Mc[i] = s * (1.0f / 2048.0f);
  }
}

// x = node_feats @ W_up / sqrt(128)   one block per node, 128 threads
__global__ __launch_bounds__(128) void k_up(const float* __restrict__ nf,
                                            const float* __restrict__ W,
                                            float* __restrict__ x, int Nn) {
  int n = blockIdx.x;
  int v = threadIdx.x;
  __shared__ float row[128];
  row[v] = nf[n * 128 + v];
  __syncthreads();
  float s = 0.f;
#pragma unroll 8
  for (int k = 0; k < 128; k++) s += row[k] * W[k * 128 + v];
  x[n * 128 + v] = s * 0.08838834764831845f;
}

__global__ void k_count(const int* __restrict__ recv, int* __restrict__ deg, int E) {
  int e = blockIdx.x * blockDim.x + threadIdx.x;
  if (e < E) atomicAdd(&deg[recv[e]], 1);
}

// exclusive scan of deg -> rowstart[0..N], cursor copy. single block 1024 threads.
__global__ __launch_bounds__(1024) void k_scan(const int* __restrict__ deg,
                                               int* __restrict__ rowstart,
                                               int* __restrict__ cursor, int Nn) {
  __shared__ int part[1024];
  int t = threadIdx.x;
  int chunk = (Nn + 1023) / 1024;
  int lo = t * chunk;
  int hi = lo + chunk; if (hi > Nn) hi = Nn; if (lo > Nn) lo = Nn;
  int s = 0;
  for (int i = lo; i < hi; i++) s += deg[i];
  part[t] = s;
  __syncthreads();
  for (int o = 1; o < 1024; o <<= 1) {
    int v = (t >= o) ? part[t - o] : 0;
    __syncthreads();
    part[t] += v;
    __syncthreads();
  }
  int base = (t == 0) ? 0 : part[t - 1];
  for (int i = lo; i < hi; i++) {
    rowstart[i] = base;
    cursor[i] = base;
    base += deg[i];
  }
  if (t == 1023) rowstart[Nn] = part[1023];
}

__global__ void k_fill(const int* __restrict__ recv, int* __restrict__ cursor,
                       int* __restrict__ elist, int E) {
  int e = blockIdx.x * blockDim.x + threadIdx.x;
  if (e < E) {
    int p = atomicAdd(&cursor[recv[e]], 1);
    elist[p] = e;
  }
}

// ---------------- main fused per-node kernel (v6) ----------------
// v5 structure, but NO min-waves launch-bound hint (both (256,4) and (256,3)
// made the allocator clamp VGPRs below the live set and spill ~400MB of
// scratch per dispatch — v2's plain (256) had zero scratch traffic), and the
// two gate passes are forced sequential so their live ranges don't overlap.
__global__ __launch_bounds__(256) void k_gather(
    const float* __restrict__ x, const float* __restrict__ edge_attrs,
    const float* __restrict__ edge_feats, const float* __restrict__ mminv,
    const float* __restrict__ mmattrs, const int* __restrict__ sender,
    const float* __restrict__ W1, const float* __restrict__ W2,
    const float* __restrict__ W3, const float* __restrict__ W4,
    const float* __restrict__ Mc, const float* __restrict__ Wd,
    const float* __restrict__ Wlin, const float* __restrict__ Wmlin,
    const int* __restrict__ rowstart, const int* __restrict__ elist,
    float* __restrict__ linm, float* __restrict__ linmm, int Nn) {
  const int n = blockIdx.x;
  const int t = threadIdx.x;
  const int lane = t & 63;
  const int start = rowstart[n], end = rowstart[n + 1];

  __shared__ float efL[16][20];   // [k][g], pad 20 (rows 16B-aligned)
  __shared__ float shL[16][20];   // [g][m]
  __shared__ float mmshL[16][4];  // [g][j]
  __shared__ float hLa[64][20];   // [k][g]
  __shared__ float hLb[64][20];
  __shared__ float msg_s[128][17];
  __shared__ float mm_s[128][5];
  __shared__ float dsum_s;

  for (int i = t; i < 128 * 17; i += 256) (&msg_s[0][0])[i] = 0.f;
  for (int i = t; i < 128 * 5; i += 256) (&mm_s[0][0])[i] = 0.f;
  if (t == 0) dsum_s = 0.f;

  const int i16 = lane & 15;
  const int gst = t >> 4;   // 0..15: edge this thread stages
  const int jst = t & 15;   // component
  const float wd_j = (jst < 8) ? Wd[jst] : 0.f;
  const int hh = t >> 7;    // 0/1: which 8 edges in the gate (wave-uniform)
  const int u = t & 127;
  const int o = lane;       // MLP output index
  const int gq = t >> 6;    // edge quad for MLP phases (wave-uniform)

  float accm[16];
  float accmm[4];
#pragma unroll
  for (int m = 0; m < 16; m++) accm[m] = 0.f;
#pragma unroll
  for (int j = 0; j < 4; j++) accmm[j] = 0.f;
  float dens_acc = 0.f;

  for (int base = start; base < end; base += 16) {
    // ---- per-wave edge indices (redundant tiny loads; no barrier needed)
    int e16 = -1, s16 = 0;
    if (base + i16 < end) {
      e16 = elist[base + i16];
      s16 = sender[e16];
    }
    const int e_st = __shfl(e16, gst);
    const int s_st = __shfl(s16, gst);
    // ---- stage ef/sh (one element each), mmsh (wave 0)
    float efv = 0.f, shv = 0.f;
    if (e_st >= 0) {
      efv = (jst < 8) ? edge_feats[e_st * 8 + jst] : mminv[s_st * 8 + jst - 8];
      shv = edge_attrs[e_st * 16 + jst];
    }
    efL[jst][gst] = efv;
    shL[gst][jst] = shv;
    if (t < 64) {
      int g4 = lane >> 2, j4 = lane & 3;
      int e4 = __shfl(e16, g4);
      int s4 = __shfl(s16, g4);
      mmshL[g4][j4] = (e4 >= 0) ? mmattrs[s4 * 4 + j4] : 0.f;
    }
    // ---- density (sum over j<8 within each 16-lane group)
    {
      float p = (jst < 8 && e_st >= 0) ? efv * wd_j : 0.f;
      p += __shfl_xor(p, 1);
      p += __shfl_xor(p, 2);
      p += __shfl_xor(p, 4);
      if (jst == 0 && e_st >= 0) {
        float q = p * 0.35355339059327373f;
        dens_acc += tanhf(q * q);
      }
    }
    __syncthreads();
    // ---- h1 = silu(ef@W1/4): thread computes 4 edges (gq) for output o
    {
      float h0 = 0.f, h1 = 0.f, h2 = 0.f, h3 = 0.f;
#pragma unroll
      for (int k = 0; k < 16; k++) {
        float wv = W1[k * 64 + o];
        float4 ea = *(const float4*)&efL[k][gq * 4];
        h0 += ea.x * wv; h1 += ea.y * wv; h2 += ea.z * wv; h3 += ea.w * wv;
      }
      *(float4*)&hLa[o][gq * 4] = make_float4(
          silu_f(h0 * 0.25f), silu_f(h1 * 0.25f), silu_f(h2 * 0.25f), silu_f(h3 * 0.25f));
    }
    __syncthreads();
    // ---- h2 = silu(h1@W2/8)
    {
      float h0 = 0.f, h1 = 0.f, h2 = 0.f, h3 = 0.f;
#pragma unroll 8
      for (int k = 0; k < 64; k++) {
        float wv = W2[k * 64 + o];
        float4 ha = *(const float4*)&hLa[k][gq * 4];
        h0 += ha.x * wv; h1 += ha.y * wv; h2 += ha.z * wv; h3 += ha.w * wv;
      }
      *(float4*)&hLb[o][gq * 4] = make_float4(
          silu_f(h0 * 0.125f), silu_f(h1 * 0.125f), silu_f(h2 * 0.125f), silu_f(h3 * 0.125f));
    }
    __syncthreads();
    // ---- h3 = silu(h2@W3/8) -> hLa
    {
      float h0 = 0.f, h1 = 0.f, h2 = 0.f, h3 = 0.f;
#pragma unroll 8
      for (int k = 0; k < 64; k++) {
        float wv = W3[k * 64 + o];
        float4 hb = *(const float4*)&hLb[k][gq * 4];
        h0 += hb.x * wv; h1 += hb.y * wv; h2 += hb.z * wv; h3 += hb.w * wv;
      }
      *(float4*)&hLa[o][gq * 4] = make_float4(
          silu_f(h0 * 0.125f), silu_f(h1 * 0.125f), silu_f(h2 * 0.125f), silu_f(h3 * 0.125f));
    }
    __syncthreads();
    // ---- gate in TWO SEQUENTIAL passes of 4 edges (unroll 1: keep the
    // passes' w4g/wmg live ranges disjoint — register pressure control)
#pragma unroll 1
    for (int pp = 0; pp < 2; pp++) {
      const int gb = hh * 8 + pp * 4;  // edges gb..gb+3 (wave-uniform)
      // w4 for channel u, 4 edges, 4 l-values
      float4 w4g[4];
#pragma unroll
      for (int i = 0; i < 4; i++) w4g[i] = make_float4(0.f, 0.f, 0.f, 0.f);
      {
        const float* W4p = W4 + u * 4;
#pragma unroll 4
        for (int k = 0; k < 64; k++) {
          float4 wv = *(const float4*)(W4p + k * 512);
          float4 ha = *(const float4*)&hLa[k][gb];
          w4g[0].x += ha.x * wv.x; w4g[0].y += ha.x * wv.y; w4g[0].z += ha.x * wv.z; w4g[0].w += ha.x * wv.w;
          w4g[1].x += ha.y * wv.x; w4g[1].y += ha.y * wv.y; w4g[1].z += ha.y * wv.z; w4g[1].w += ha.y * wv.w;
          w4g[2].x += ha.z * wv.x; w4g[2].y += ha.z * wv.y; w4g[2].z += ha.z * wv.z; w4g[2].w += ha.z * wv.w;
          w4g[3].x += ha.w * wv.x; w4g[3].y += ha.w * wv.y; w4g[3].z += ha.w * wv.z; w4g[3].w += ha.w * wv.w;
        }
      }
      // wmm for channel u, 4 edges
      float2 wmg[4];
#pragma unroll
      for (int i = 0; i < 4; i++) wmg[i] = make_float2(0.f, 0.f);
      {
        const float* Mcp = Mc + u * 2;
#pragma unroll 4
        for (int k = 0; k < 16; k++) {
          float2 mv = *(const float2*)(Mcp + k * 256);
          float4 ea = *(const float4*)&efL[k][gb];
          wmg[0].x += ea.x * mv.x; wmg[0].y += ea.x * mv.y;
          wmg[1].x += ea.y * mv.x; wmg[1].y += ea.y * mv.y;
          wmg[2].x += ea.z * mv.x; wmg[2].y += ea.z * mv.y;
          wmg[3].x += ea.w * mv.x; wmg[3].y += ea.w * mv.y;
        }
      }
      // gate chain + SH accumulation for these 4 edges
#pragma unroll
      for (int i = 0; i < 4; i++) {
        int g = gb + i;
        int sg = __shfl(s16, g);
        float xv = x[(size_t)sg * 128 + u];
        float4 s0 = *(const float4*)&shL[g][0];
        float4 s4 = *(const float4*)&shL[g][4];
        float4 s8 = *(const float4*)&shL[g][8];
        float4 s12 = *(const float4*)&shL[g][12];
        float4 mh = *(const float4*)&mmshL[g][0];
        float w40 = w4g[i].x * 0.125f, w41 = w4g[i].y * 0.125f;
        float w42 = w4g[i].z * 0.125f, w43 = w4g[i].w * 0.125f;
        float pre0 = w40 * xv * s0.x;
        float wg0 = wmg[i].x * pre0;
        float wg1 = wmg[i].y * pre0;
        float mm0 = wg0 * xv * mh.x;
        float c = wg1 * xv;
        float bx = mm0 * xv;
        float a0 = w40 * bx, a1 = w41 * bx, a2 = w42 * bx, a3 = w43 * bx;
        accmm[0] += mm0;
        accmm[1] += c * mh.y;
        accmm[2] += c * mh.z;
        accmm[3] += c * mh.w;
        accm[0] += a0 * s0.x;
        accm[1] += a1 * s0.y;
        accm[2] += a1 * s0.z;
        accm[3] += a1 * s0.w;
        accm[4] += a2 * s4.x;
        accm[5] += a2 * s4.y;
        accm[6] += a2 * s4.z;
        accm[7] += a2 * s4.w;
        accm[8] += a2 * s8.x;
        accm[9] += a3 * s8.y;
        accm[10] += a3 * s8.z;
        accm[11] += a3 * s8.w;
        accm[12] += a3 * s12.x;
        accm[13] += a3 * s12.y;
        accm[14] += a3 * s12.z;
        accm[15] += a3 * s12.w;
      }
    }
    __syncthreads();  // protect efL/shL/hLa/mmshL before next chunk's staging
  }

  // ---- block reduction (t and t+128 share u)
#pragma unroll
  for (int m = 0; m < 16; m++) atomicAdd(&msg_s[u][m], accm[m]);
#pragma unroll
  for (int j = 0; j < 4; j++) atomicAdd(&mm_s[u][j], accmm[j]);
  if (jst == 0) atomicAdd(&dsum_s, dens_acc);
  __syncthreads();

  // ---- epilogue: per_l_linear + density divide (msg), W_mlin + /20 (mm)
  const int uo = t & 127;
  const int half = t >> 7;
  const float dinv = 1.0f / (dsum_s + 1.0f);

  float outl[8] = {0, 0, 0, 0, 0, 0, 0, 0};
  if (half == 0) {
    for (int uu = 0; uu < 128; uu++) {
      float wl0 = Wlin[uu * 128 + uo];
      float wl1 = Wlin[16384 + uu * 128 + uo];
      float wl2 = Wlin[32768 + uu * 128 + uo];
      outl[0] += msg_s[uu][0] * wl0;
      outl[1] += msg_s[uu][1] * wl1;
      outl[2] += msg_s[uu][2] * wl1;
      outl[3] += msg_s[uu][3] * wl1;
      outl[4] += msg_s[uu][4] * wl2;
      outl[5] += msg_s[uu][5] * wl2;
      outl[6] += msg_s[uu][6] * wl2;
      outl[7] += msg_s[uu][7] * wl2;
    }
  } else {
    for (int uu = 0; uu < 128; uu++) {
      float wl2 = Wlin[32768 + uu * 128 + uo];
      float wl3 = Wlin[49152 + uu * 128 + uo];
      outl[0] += msg_s[uu][8] * wl2;
      outl[1] += msg_s[uu][9] * wl3;
      outl[2] += msg_s[uu][10] * wl3;
      outl[3] += msg_s[uu][11] * wl3;
      outl[4] += msg_s[uu][12] * wl3;
      outl[5] += msg_s[uu][13] * wl3;
      outl[6] += msg_s[uu][14] * wl3;
      outl[7] += msg_s[uu][15] * wl3;
    }
  }
  const float scl = 0.08838834764831845f * dinv;
  float4 v0 = make_float4(outl[0] * scl, outl[1] * scl, outl[2] * scl, outl[3] * scl);
  float4 v1 = make_float4(outl[4] * scl, outl[5] * scl, outl[6] * scl, outl[7] * scl);
  float4* lp = (float4*)(linm + (size_t)n * 2048 + uo * 16 + half * 8);
  lp[0] = v0;
  lp[1] = v1;

  float om0 = 0.f, om1 = 0.f;
  if (half == 0) {
    for (int uu = 0; uu < 128; uu++) {
      om0 += mm_s[uu][0] * Wmlin[uu * 128 + uo];
      om1 += mm_s[uu][1] * Wmlin[16384 + uu * 128 + uo];
    }
  } else {
    for (int uu = 0; uu < 128; uu++) {
      float wm1 = Wmlin[16384 + uu * 128 + uo];
      om0 += mm_s[uu][2] * wm1;
      om1 += mm_s[uu][3] * wm1;
    }
  }
  const float sm = 0.08838834764831845f / 20.0f;
  *(float2*)(linmm + (size_t)n * 512 + uo * 4 + half * 2) = make_float2(om0 * sm, om1 * sm);
}

// zero out2 blocks l=2,3 (no path -> zero)
__global__ void k_zero2(float* __restrict__ out2, int Nn) {
  int i = blockIdx.x * blockDim.x + threadIdx.x;
  if (i < Nn * 128) {
    float4 z = make_float4(0.f, 0.f, 0.f, 0.f);
    float4* p = (float4*)(out2 + (size_t)i * 16);
    p[1] = z;
    p[2] = z;
    p[3] = z;
  }
}

// ---------------- skip tensor product (barrier-free inner loop) ----------
__global__ __launch_bounds__(128) void k_wt(const float* __restrict__ Wskip,
                                            const float* __restrict__ Wmskip,
                                            float* __restrict__ Wt) {
  int bx = blockIdx.x;              // 0..767 : L = bx>>7, u = bx&127
  int L = bx >> 7, u = bx & 127;
  int v = threadIdx.x;
  const float* src = (L < 4) ? (Wskip + (size_t)L * 163840)
                             : (Wmskip + (size_t)(L - 4) * 163840);
  float* dst = Wt + (((size_t)L * 128 + u) * 128 + v) * 12;
#pragma unroll
  for (int z = 0; z < 10; z++) dst[z] = src[u * 1280 + z * 128 + v];
  dst[10] = 0.f;
  dst[11] = 0.f;
}

// out[n,v,off+m] = (1/sqrt(1280)) * sum_u in[n,u,m] * (sum_z attrs[n,z]*Wt[u,v,z])
template <int D, int SP>
__device__ __forceinline__ void skip_body2(
    const float* __restrict__ attrs, const float* __restrict__ in, int in_rs,
    int in_us, int in_cb, const float* __restrict__ Wt, float* __restrict__ outp,
    int out_cb, int Nn, int n0, float* lin_s, float (*attrs_s)[10]) {
  const int t = threadIdx.x;
  for (int i = t; i < 160; i += 256) {
    int nn = i / 10, z = i - nn * 10;
    int n = n0 + nn;
    attrs_s[nn][z] = (n < Nn) ? attrs[n * 10 + z] : 0.f;
  }
  for (int i = t; i < 16 * 128 * D; i += 256) {
    int nn = i / (128 * D);
    int r = i - nn * 128 * D;
    int uu = r / D;
    int m = r - uu * D;
    int n = n0 + nn;
    lin_s[(nn * 128 + uu) * SP + m] =
        (n < Nn) ? in[(size_t)n * in_rs + uu * in_us + in_cb + m] : 0.f;
  }
  __syncthreads();

  const int v = t & 127, hf = t >> 7;
  float ar[8][10];
#pragma unroll
  for (int q = 0; q < 8; q++)
#pragma unroll
    for (int z = 0; z < 10; z++) ar[q][z] = attrs_s[hf * 8 + q][z];

  float acc[8][D];
#pragma unroll
  for (int q = 0; q < 8; q++)
#pragma unroll
    for (int m = 0; m < D; m++) acc[q][m] = 0.f;

  const float* wp0 = Wt + (size_t)v * 12;
  for (int u = 0; u < 128; u++) {
    const float* wp = wp0 + (size_t)u * 1536;  // 128*12
    float4 wa = *(const float4*)wp;
    float4 wb = *(const float4*)(wp + 4);
    float2 wc = *(const float2*)(wp + 8);
    float wr[10] = {wa.x, wa.y, wa.z, wa.w, wb.x, wb.y, wb.z, wb.w, wc.x, wc.y};
#pragma unroll
    for (int q = 0; q < 8; q++) {
      float wn = 0.f;
#pragma unroll
      for (int z = 0; z < 10; z++) wn += ar[q][z] * wr[z];
      const float* ls = &lin_s[((hf * 8 + q) * 128 + u) * SP];
#pragma unroll
      for (int m = 0; m < D; m++) acc[q][m] += ls[m] * wn;
    }
  }
#pragma unroll
  for (int q = 0; q < 8; q++) {
    int n = n0 + hf * 8 + q;
    if (n < Nn) {
      float* op = outp + (size_t)n * 2048 + v * 16 + out_cb;
#pragma unroll
      for (int m = 0; m < D; m++) op[m] = acc[q][m] * 0.027950849718747371f;
    }
  }
}

__global__ __launch_bounds__(256) void k_skip(
    const float* __restrict__ attrs, const float* __restrict__ linm,
    const float* __restrict__ linmm, const float* __restrict__ Wt,
    float* __restrict__ out, int Nn) {
  __shared__ float lin_s[16 * 128 * 8];
  __shared__ float attrs_s[16][10];
  const int n0 = blockIdx.x * 16;
  const int job = blockIdx.y;
  const float* Wtj = Wt + (size_t)job * 128 * 128 * 12;
  switch (job) {
    case 0: skip_body2<1, 1>(attrs, linm, 2048, 16, 0, Wtj, out, 0, Nn, n0, lin_s, attrs_s); break;
    case 1: skip_body2<3, 4>(attrs, linm, 2048, 16, 1, Wtj, out, 1, Nn, n0, lin_s, attrs_s); break;
    case 2: skip_body2<5, 8>(attrs, linm, 2048, 16, 4, Wtj, out, 4, Nn, n0, lin_s, attrs_s); break;
    case 3: skip_body2<7, 8>(attrs, linm, 2048, 16, 9, Wtj, out, 9, Nn, n0, lin_s, attrs_s); break;
    case 4: skip_body2<1, 1>(attrs, linmm, 512, 4, 0, Wtj, out + (size_t)Nn * 2048, 0, Nn, n0, lin_s, attrs_s); break;
    case 5: skip_body2<3, 4>(attrs, linmm, 512, 4, 1, Wtj, out + (size_t)Nn * 2048, 1, Nn, n0, lin_s, attrs_s); break;
  }
}

extern "C" void kernel_launch(void* const* d_in, const int* in_sizes, int n_in,
                              void* d_out, int out_size, void* d_ws, size_t ws_size,
                              hipStream_t stream) {
  const float* node_attrs = (const float*)d_in[0];
  const float* node_feats = (const float*)d_in[1];
  const float* edge_attrs = (const float*)d_in[2];
  const float* edge_feats = (const float*)d_in[3];
  const float* mminv = (const float*)d_in[4];
  const float* mmattrs = (const float*)d_in[5];
  const int* edge_index = (const int*)d_in[6];
  const float* W_up = (const float*)d_in[7];
  const float* W1 = (const float*)d_in[8];
  const float* W2 = (const float*)d_in[9];
  const float* W3 = (const float*)d_in[10];
  const float* W4 = (const float*)d_in[11];
  const float* M1 = (const float*)d_in[12];
  const float* M2 = (const float*)d_in[13];
  const float* M3 = (const float*)d_in[14];
  const float* M4 = (const float*)d_in[15];
  const float* Wd = (const float*)d_in[16];
  const float* Wlin = (const float*)d_in[17];
  const float* Wmlin = (const float*)d_in[18];
  const float* Wskip = (const float*)d_in[19];
  const float* Wmskip = (const float*)d_in[20];

  const int N = in_sizes[1] / 128;
  const int E = in_sizes[2] / 16;
  const int* sender = edge_index;
  const int* recv = edge_index + E;

  float* ws = (float*)d_ws;
  float* x = ws;        ws += (size_t)N * 128;
  float* Mc = ws;       ws += 16 * 256;
  float* linm = ws;     ws += (size_t)N * 2048;
  float* linmm = ws;    ws += (size_t)N * 512;
  float* Wt = ws;       ws += (size_t)6 * 128 * 128 * 12;
  int* ibuf = (int*)ws;
  int* rowstart = ibuf;            // N+1
  int* deg = ibuf + (N + 1);       // N
  int* cursor = deg + N;           // N
  int* elist = cursor + N;         // E

  k_zero_int<<<(N + 255) / 256, 256, 0, stream>>>(deg, N);
  k_prep<<<1, 256, 0, stream>>>(M1, M2, M3, M4, Mc);
  k_wt<<<768, 128, 0, stream>>>(Wskip, Wmskip, Wt);
  k_up<<<N, 128, 0, stream>>>(node_feats, W_up, x, N);
  k_count<<<(E + 255) / 256, 256, 0, stream>>>(recv, deg, E);
  k_scan<<<1, 1024, 0, stream>>>(deg, rowstart, cursor, N);
  k_fill<<<(E + 255) / 256, 256, 0, stream>>>(recv, cursor, elist, E);
  k_gather<<<N, 256, 0, stream>>>(x, edge_attrs, edge_feats, mminv, mmattrs,
                                  sender, W1, W2, W3, W4, Mc, Wd, Wlin, Wmlin,
                                  rowstart, elist, linm, linmm, N);
  k_zero2<<<(N * 128 + 255) / 256, 256, 0, stream>>>((float*)d_out + (size_t)N * 2048, N);
  dim3 gs((N + 15) / 16, 6);
  k_skip<<<gs, 256, 0, stream>>>(node_attrs, linm, linmm, Wt, (float*)d_out, N);
}

// Round 7
// 1068.626 us; speedup vs baseline: 1.2588x; 1.2588x over previous
//
#include <hip/hip_runtime.h>

// MUL=128, Z=10, L_DIMS=(1,3,5,7) offs (0,1,4,9), MM_DIMS=(1,3)

__device__ __forceinline__ float silu_f(float x) {
  return x / (1.0f + __expf(-x));
}

__global__ void k_zero_int(int* p, int n) {
  int i = blockIdx.x * blockDim.x + threadIdx.x;
  if (i < n) p[i] = 0;
}

// Mc = M1@M2@M3@M4 / 2048  (linear MLP collapse), Mc is [16,256]
__global__ __launch_bounds__(256) void k_prep(
    const float* __restrict__ M1, const float* __restrict__ M2,
    const float* __restrict__ M3, const float* __restrict__ M4,
    float* __restrict__ Mc) {
  __shared__ float T1[16 * 64];
  __shared__ float T2[16 * 64];
  int t = threadIdx.x;
  for (int i = t; i < 16 * 64; i += 256) {
    int r = i >> 6, c = i & 63;
    float s = 0.f;
    for (int k = 0; k < 64; k++) s += M1[r * 64 + k] * M2[k * 64 + c];
    T1[i] = s;
  }
  __syncthreads();
  for (int i = t; i < 16 * 64; i += 256) {
    int r = i >> 6, c = i & 63;
    float s = 0.f;
    for (int k = 0; k < 64; k++) s += T1[r * 64 + k] * M3[k * 64 + c];
    T2[i] = s;
  }
  __syncthreads();
  for (int i = t; i < 16 * 256; i += 256) {
    int r = i >> 8, c = i & 255;
    float s = 0.f;
    for (int k = 0; k < 64; k++) s += T2[r * 64 + k] * M4[k * 256 + c];
    Mc[i] = s * (1.0f / 2048.0f);
  }
}

// x = node_feats @ W_up / sqrt(128)
__global__ __launch_bounds__(128) void k_up(const float* __restrict__ nf,
                                            const float* __restrict__ W,
                                            float* __restrict__ x, int Nn) {
  int n = blockIdx.x;
  int v = threadIdx.x;
  __shared__ float row[128];
  row[v] = nf[n * 128 + v];
  __syncthreads();
  float s = 0.f;
#pragma unroll 8
  for (int k = 0; k < 128; k++) s += row[k] * W[k * 128 + v];
  x[n * 128 + v] = s * 0.08838834764831845f;
}

__global__ void k_count(const int* __restrict__ recv, int* __restrict__ deg, int E) {
  int e = blockIdx.x * blockDim.x + threadIdx.x;
  if (e < E) atomicAdd(&deg[recv[e]], 1);
}

__global__ __launch_bounds__(1024) void k_scan(const int* __restrict__ deg,
                                               int* __restrict__ rowstart,
                                               int* __restrict__ cursor, int Nn) {
  __shared__ int part[1024];
  int t = threadIdx.x;
  int chunk = (Nn + 1023) / 1024;
  int lo = t * chunk;
  int hi = lo + chunk; if (hi > Nn) hi = Nn; if (lo > Nn) lo = Nn;
  int s = 0;
  for (int i = lo; i < hi; i++) s += deg[i];
  part[t] = s;
  __syncthreads();
  for (int o = 1; o < 1024; o <<= 1) {
    int v = (t >= o) ? part[t - o] : 0;
    __syncthreads();
    part[t] += v;
    __syncthreads();
  }
  int base = (t == 0) ? 0 : part[t - 1];
  for (int i = lo; i < hi; i++) {
    rowstart[i] = base;
    cursor[i] = base;
    base += deg[i];
  }
  if (t == 1023) rowstart[Nn] = part[1023];
}

__global__ void k_fill(const int* __restrict__ recv, int* __restrict__ cursor,
                       int* __restrict__ elist, int E) {
  int e = blockIdx.x * blockDim.x + threadIdx.x;
  if (e < E) {
    int p = atomicAdd(&cursor[recv[e]], 1);
    elist[p] = e;
  }
}

// ---------------- edge-parallel radial MLP (v7) ----------------
// 32 edges/block, 3 barriers total. Outputs w4out[e][u][l] (float4 per u,
// pre-scaled by 0.125) and dens[e]. Massive TLP: E/32 independent blocks.
__global__ __launch_bounds__(256) void k_mlp(
    const float* __restrict__ edge_feats, const float* __restrict__ mminv,
    const int* __restrict__ sender, const float* __restrict__ W1,
    const float* __restrict__ W2, const float* __restrict__ W3,
    const float* __restrict__ W4, const float* __restrict__ Wd,
    float* __restrict__ w4out, float* __restrict__ dens, int E) {
  const int t = threadIdx.x;
  const int e0 = blockIdx.x * 32;
  __shared__ float efL[16][33];  // [j][e], pad 33 breaks staging conflicts
  __shared__ float hA[64][32];   // [o][e]
  __shared__ float hB[64][32];

  // stage ef_mm
  for (int i = t; i < 512; i += 256) {
    int g = i >> 4, j = i & 15;
    int e = e0 + g;
    float v = 0.f;
    if (e < E) {
      int s = sender[e];
      v = (j < 8) ? edge_feats[e * 8 + j] : mminv[s * 8 + (j - 8)];
    }
    efL[j][g] = v;
  }
  // density
  if (t < 32 && e0 + t < E) {
    float q = 0.f;
#pragma unroll
    for (int j = 0; j < 8; j++) q += edge_feats[(e0 + t) * 8 + j] * Wd[j];
    q *= 0.35355339059327373f;
    dens[e0 + t] = tanhf(q * q);
  }
  __syncthreads();

  const int e = t & 31;   // edge lane
  const int og = t >> 5;  // output octet
  const int ob = og * 8;
  float h[8];
  // h1 = silu(ef@W1/4)
#pragma unroll
  for (int m = 0; m < 8; m++) h[m] = 0.f;
#pragma unroll
  for (int k = 0; k < 16; k++) {
    float ev = efL[k][e];
    float4 wa = *(const float4*)&W1[k * 64 + ob];
    float4 wb = *(const float4*)&W1[k * 64 + ob + 4];
    h[0] += ev * wa.x; h[1] += ev * wa.y; h[2] += ev * wa.z; h[3] += ev * wa.w;
    h[4] += ev * wb.x; h[5] += ev * wb.y; h[6] += ev * wb.z; h[7] += ev * wb.w;
  }
#pragma unroll
  for (int m = 0; m < 8; m++) hA[ob + m][e] = silu_f(h[m] * 0.25f);
  __syncthreads();
  // h2 = silu(h1@W2/8)
#pragma unroll
  for (int m = 0; m < 8; m++) h[m] = 0.f;
#pragma unroll 8
  for (int k = 0; k < 64; k++) {
    float ev = hA[k][e];
    float4 wa = *(const float4*)&W2[k * 64 + ob];
    float4 wb = *(const float4*)&W2[k * 64 + ob + 4];
    h[0] += ev * wa.x; h[1] += ev * wa.y; h[2] += ev * wa.z; h[3] += ev * wa.w;
    h[4] += ev * wb.x; h[5] += ev * wb.y; h[6] += ev * wb.z; h[7] += ev * wb.w;
  }
#pragma unroll
  for (int m = 0; m < 8; m++) hB[ob + m][e] = silu_f(h[m] * 0.125f);
  __syncthreads();
  // h3 = silu(h2@W3/8) -> hA
#pragma unroll
  for (int m = 0; m < 8; m++) h[m] = 0.f;
#pragma unroll 8
  for (int k = 0; k < 64; k++) {
    float ev = hB[k][e];
    float4 wa = *(const float4*)&W3[k * 64 + ob];
    float4 wb = *(const float4*)&W3[k * 64 + ob + 4];
    h[0] += ev * wa.x; h[1] += ev * wa.y; h[2] += ev * wa.z; h[3] += ev * wa.w;
    h[4] += ev * wb.x; h[5] += ev * wb.y; h[6] += ev * wb.z; h[7] += ev * wb.w;
  }
#pragma unroll
  for (int m = 0; m < 8; m++) hA[ob + m][e] = silu_f(h[m] * 0.125f);
  __syncthreads();

  // w4 = h3@W4/8 : thread owns u = t&127 (columns u*4..u*4+3), half the edges
  const int u = t & 127;
  const int eh = t >> 7;
  const float* W4c = W4 + u * 4;
#pragma unroll 1
  for (int eg = 0; eg < 4; eg++) {
    const int eb = eh * 16 + eg * 4;
    float4 a0 = make_float4(0.f, 0.f, 0.f, 0.f);
    float4 a1 = a0, a2 = a0, a3 = a0;
#pragma unroll 4
    for (int k = 0; k < 64; k++) {
      float4 wv = *(const float4*)(W4c + k * 512);
      float4 hv = *(const float4*)&hA[k][eb];
      a0.x += hv.x * wv.x; a0.y += hv.x * wv.y; a0.z += hv.x * wv.z; a0.w += hv.x * wv.w;
      a1.x += hv.y * wv.x; a1.y += hv.y * wv.y; a1.z += hv.y * wv.z; a1.w += hv.y * wv.w;
      a2.x += hv.z * wv.x; a2.y += hv.z * wv.y; a2.z += hv.z * wv.z; a2.w += hv.z * wv.w;
      a3.x += hv.w * wv.x; a3.y += hv.w * wv.y; a3.z += hv.w * wv.z; a3.w += hv.w * wv.w;
    }
    const float s = 0.125f;
    int ea = e0 + eb;
    if (ea + 0 < E) *(float4*)&w4out[(size_t)(ea + 0) * 512 + u * 4] =
        make_float4(a0.x * s, a0.y * s, a0.z * s, a0.w * s);
    if (ea + 1 < E) *(float4*)&w4out[(size_t)(ea + 1) * 512 + u * 4] =
        make_float4(a1.x * s, a1.y * s, a1.z * s, a1.w * s);
    if (ea + 2 < E) *(float4*)&w4out[(size_t)(ea + 2) * 512 + u * 4] =
        make_float4(a2.x * s, a2.y * s, a2.z * s, a2.w * s);
    if (ea + 3 < E) *(float4*)&w4out[(size_t)(ea + 3) * 512 + u * 4] =
        make_float4(a3.x * s, a3.y * s, a3.z * s, a3.w * s);
  }
}

// ---------------- per-node gate + scatter + epilogue (v7) ----------------
// Pure streaming: per edge per thread one float4 w4out read, wmm from Mc
// held in registers, LDS-broadcast sh. 2 barriers per 16-edge chunk.
__global__ __launch_bounds__(256) void k_gate(
    const float* __restrict__ x, const float* __restrict__ edge_attrs,
    const float* __restrict__ edge_feats, const float* __restrict__ mminv,
    const float* __restrict__ mmattrs, const int* __restrict__ sender,
    const float* __restrict__ Mc, const float* __restrict__ w4out,
    const float* __restrict__ dens, const float* __restrict__ Wlin,
    const float* __restrict__ Wmlin, const int* __restrict__ rowstart,
    const int* __restrict__ elist, float* __restrict__ linm,
    float* __restrict__ linmm, int Nn) {
  const int n = blockIdx.x;
  const int t = threadIdx.x;
  const int lane = t & 63;
  const int start = rowstart[n], end = rowstart[n + 1];

  __shared__ float efL[16][20];   // [j][g]
  __shared__ float shL[16][20];   // [g][m]
  __shared__ float mmshL[16][4];  // [g][j]
  __shared__ float msg_s[128][17];
  __shared__ float mm_s[128][5];
  __shared__ float dsum_s;

  for (int i = t; i < 128 * 17; i += 256) (&msg_s[0][0])[i] = 0.f;
  for (int i = t; i < 128 * 5; i += 256) (&mm_s[0][0])[i] = 0.f;
  if (t == 0) dsum_s = 0.f;

  const int i16 = lane & 15;
  const int gst = t >> 4;
  const int jst = t & 15;
  const int hh = t >> 7;
  const int u = t & 127;

  // Mc columns for this u, kept in registers
  float2 mc[16];
#pragma unroll
  for (int k = 0; k < 16; k++) mc[k] = *(const float2*)&Mc[k * 256 + u * 2];

  float accm[16];
  float accmm[4];
#pragma unroll
  for (int m = 0; m < 16; m++) accm[m] = 0.f;
#pragma unroll
  for (int j = 0; j < 4; j++) accmm[j] = 0.f;
  float dens_acc = 0.f;

  for (int base = start; base < end; base += 16) {
    int e16 = -1, s16 = 0;
    if (base + i16 < end) {
      e16 = elist[base + i16];
      s16 = sender[e16];
    }
    const int e_st = __shfl(e16, gst);
    const int s_st = __shfl(s16, gst);
    float efv = 0.f, shv = 0.f;
    if (e_st >= 0) {
      efv = (jst < 8) ? edge_feats[e_st * 8 + jst] : mminv[s_st * 8 + jst - 8];
      shv = edge_attrs[e_st * 16 + jst];
    }
    efL[jst][gst] = efv;
    shL[gst][jst] = shv;
    if (t < 64) {
      int g4 = lane >> 2, j4 = lane & 3;
      int e4 = __shfl(e16, g4);
      int s4 = __shfl(s16, g4);
      mmshL[g4][j4] = (e4 >= 0) ? mmattrs[s4 * 4 + j4] : 0.f;
    }
    if (jst == 0 && e_st >= 0) dens_acc += dens[e_st];
    __syncthreads();

#pragma unroll 1
    for (int i = 0; i < 8; i++) {
      const int g = hh * 8 + i;  // wave-uniform
      const int eg = __shfl(e16, g);
      if (eg < 0) break;
      const int sg = __shfl(s16, g);
      float4 w4 = *(const float4*)&w4out[(size_t)eg * 512 + u * 4];  // pre-scaled
      float xv = x[(size_t)sg * 128 + u];
      // wmm from Mc registers + ef broadcasts
      float wm0 = 0.f, wm1 = 0.f;
#pragma unroll
      for (int k = 0; k < 16; k++) {
        float ev = efL[k][g];
        wm0 += ev * mc[k].x;
        wm1 += ev * mc[k].y;
      }
      float4 s0 = *(const float4*)&shL[g][0];
      float4 s4 = *(const float4*)&shL[g][4];
      float4 s8 = *(const float4*)&shL[g][8];
      float4 s12 = *(const float4*)&shL[g][12];
      float4 mh = *(const float4*)&mmshL[g][0];
      float pre0 = w4.x * xv * s0.x;
      float wg0 = wm0 * pre0;
      float wg1 = wm1 * pre0;
      float mm0 = wg0 * xv * mh.x;
      float c = wg1 * xv;
      float bx = mm0 * xv;
      float a0 = w4.x * bx, a1 = w4.y * bx, a2 = w4.z * bx, a3 = w4.w * bx;
      accmm[0] += mm0;
      accmm[1] += c * mh.y;
      accmm[2] += c * mh.z;
      accmm[3] += c * mh.w;
      accm[0] += a0 * s0.x;
      accm[1] += a1 * s0.y;
      accm[2] += a1 * s0.z;
      accm[3] += a1 * s0.w;
      accm[4] += a2 * s4.x;
      accm[5] += a2 * s4.y;
      accm[6] += a2 * s4.z;
      accm[7] += a2 * s4.w;
      accm[8] += a2 * s8.x;
      accm[9] += a3 * s8.y;
      accm[10] += a3 * s8.z;
      accm[11] += a3 * s8.w;
      accm[12] += a3 * s12.x;
      accm[13] += a3 * s12.y;
      accm[14] += a3 * s12.z;
      accm[15] += a3 * s12.w;
    }
    __syncthreads();
  }

  // ---- block reduction (t and t+128 share u)
#pragma unroll
  for (int m = 0; m < 16; m++) atomicAdd(&msg_s[u][m], accm[m]);
#pragma unroll
  for (int j = 0; j < 4; j++) atomicAdd(&mm_s[u][j], accmm[j]);
  if (jst == 0) atomicAdd(&dsum_s, dens_acc);
  __syncthreads();

  // ---- epilogue: per_l_linear + density divide (msg), W_mlin + /20 (mm)
  const int uo = t & 127;
  const int half = t >> 7;
  const float dinv = 1.0f / (dsum_s + 1.0f);

  float outl[8] = {0, 0, 0, 0, 0, 0, 0, 0};
  if (half == 0) {
    for (int uu = 0; uu < 128; uu++) {
      float wl0 = Wlin[uu * 128 + uo];
      float wl1 = Wlin[16384 + uu * 128 + uo];
      float wl2 = Wlin[32768 + uu * 128 + uo];
      outl[0] += msg_s[uu][0] * wl0;
      outl[1] += msg_s[uu][1] * wl1;
      outl[2] += msg_s[uu][2] * wl1;
      outl[3] += msg_s[uu][3] * wl1;
      outl[4] += msg_s[uu][4] * wl2;
      outl[5] += msg_s[uu][5] * wl2;
      outl[6] += msg_s[uu][6] * wl2;
      outl[7] += msg_s[uu][7] * wl2;
    }
  } else {
    for (int uu = 0; uu < 128; uu++) {
      float wl2 = Wlin[32768 + uu * 128 + uo];
      float wl3 = Wlin[49152 + uu * 128 + uo];
      outl[0] += msg_s[uu][8] * wl2;
      outl[1] += msg_s[uu][9] * wl3;
      outl[2] += msg_s[uu][10] * wl3;
      outl[3] += msg_s[uu][11] * wl3;
      outl[4] += msg_s[uu][12] * wl3;
      outl[5] += msg_s[uu][13] * wl3;
      outl[6] += msg_s[uu][14] * wl3;
      outl[7] += msg_s[uu][15] * wl3;
    }
  }
  const float scl = 0.08838834764831845f * dinv;
  float4 v0 = make_float4(outl[0] * scl, outl[1] * scl, outl[2] * scl, outl[3] * scl);
  float4 v1 = make_float4(outl[4] * scl, outl[5] * scl, outl[6] * scl, outl[7] * scl);
  float4* lp = (float4*)(linm + (size_t)n * 2048 + uo * 16 + half * 8);
  lp[0] = v0;
  lp[1] = v1;

  float om0 = 0.f, om1 = 0.f;
  if (half == 0) {
    for (int uu = 0; uu < 128; uu++) {
      om0 += mm_s[uu][0] * Wmlin[uu * 128 + uo];
      om1 += mm_s[uu][1] * Wmlin[16384 + uu * 128 + uo];
    }
  } else {
    for (int uu = 0; uu < 128; uu++) {
      float wm1 = Wmlin[16384 + uu * 128 + uo];
      om0 += mm_s[uu][2] * wm1;
      om1 += mm_s[uu][3] * wm1;
    }
  }
  const float sm = 0.08838834764831845f / 20.0f;
  *(float2*)(linmm + (size_t)n * 512 + uo * 4 + half * 2) = make_float2(om0 * sm, om1 * sm);
}

// ---------------- fallback fused kernel (v6) — used if ws too small --------
__global__ __launch_bounds__(256) void k_gather(
    const float* __restrict__ x, const float* __restrict__ edge_attrs,
    const float* __restrict__ edge_feats, const float* __restrict__ mminv,
    const float* __restrict__ mmattrs, const int* __restrict__ sender,
    const float* __restrict__ W1, const float* __restrict__ W2,
    const float* __restrict__ W3, const float* __restrict__ W4,
    const float* __restrict__ Mc, const float* __restrict__ Wd,
    const float* __restrict__ Wlin, const float* __restrict__ Wmlin,
    const int* __restrict__ rowstart, const int* __restrict__ elist,
    float* __restrict__ linm, float* __restrict__ linmm, int Nn) {
  const int n = blockIdx.x;
  const int t = threadIdx.x;
  const int lane = t & 63;
  const int start = rowstart[n], end = rowstart[n + 1];

  __shared__ float efL[16][20];
  __shared__ float shL[16][20];
  __shared__ float mmshL[16][4];
  __shared__ float hLa[64][20];
  __shared__ float hLb[64][20];
  __shared__ float msg_s[128][17];
  __shared__ float mm_s[128][5];
  __shared__ float dsum_s;

  for (int i = t; i < 128 * 17; i += 256) (&msg_s[0][0])[i] = 0.f;
  for (int i = t; i < 128 * 5; i += 256) (&mm_s[0][0])[i] = 0.f;
  if (t == 0) dsum_s = 0.f;

  const int i16 = lane & 15;
  const int gst = t >> 4;
  const int jst = t & 15;
  const float wd_j = (jst < 8) ? Wd[jst] : 0.f;
  const int hh = t >> 7;
  const int u = t & 127;
  const int o = lane;
  const int gq = t >> 6;

  float accm[16];
  float accmm[4];
#pragma unroll
  for (int m = 0; m < 16; m++) accm[m] = 0.f;
#pragma unroll
  for (int j = 0; j < 4; j++) accmm[j] = 0.f;
  float dens_acc = 0.f;

  for (int base = start; base < end; base += 16) {
    int e16 = -1, s16 = 0;
    if (base + i16 < end) {
      e16 = elist[base + i16];
      s16 = sender[e16];
    }
    const int e_st = __shfl(e16, gst);
    const int s_st = __shfl(s16, gst);
    float efv = 0.f, shv = 0.f;
    if (e_st >= 0) {
      efv = (jst < 8) ? edge_feats[e_st * 8 + jst] : mminv[s_st * 8 + jst - 8];
      shv = edge_attrs[e_st * 16 + jst];
    }
    efL[jst][gst] = efv;
    shL[gst][jst] = shv;
    if (t < 64) {
      int g4 = lane >> 2, j4 = lane & 3;
      int e4 = __shfl(e16, g4);
      int s4 = __shfl(s16, g4);
      mmshL[g4][j4] = (e4 >= 0) ? mmattrs[s4 * 4 + j4] : 0.f;
    }
    {
      float p = (jst < 8 && e_st >= 0) ? efv * wd_j : 0.f;
      p += __shfl_xor(p, 1);
      p += __shfl_xor(p, 2);
      p += __shfl_xor(p, 4);
      if (jst == 0 && e_st >= 0) {
        float q = p * 0.35355339059327373f;
        dens_acc += tanhf(q * q);
      }
    }
    __syncthreads();
    {
      float h0 = 0.f, h1 = 0.f, h2 = 0.f, h3 = 0.f;
#pragma unroll
      for (int k = 0; k < 16; k++) {
        float wv = W1[k * 64 + o];
        float4 ea = *(const float4*)&efL[k][gq * 4];
        h0 += ea.x * wv; h1 += ea.y * wv; h2 += ea.z * wv; h3 += ea.w * wv;
      }
      *(float4*)&hLa[o][gq * 4] = make_float4(
          silu_f(h0 * 0.25f), silu_f(h1 * 0.25f), silu_f(h2 * 0.25f), silu_f(h3 * 0.25f));
    }
    __syncthreads();
    {
      float h0 = 0.f, h1 = 0.f, h2 = 0.f, h3 = 0.f;
#pragma unroll 8
      for (int k = 0; k < 64; k++) {
        float wv = W2[k * 64 + o];
        float4 ha = *(const float4*)&hLa[k][gq * 4];
        h0 += ha.x * wv; h1 += ha.y * wv; h2 += ha.z * wv; h3 += ha.w * wv;
      }
      *(float4*)&hLb[o][gq * 4] = make_float4(
          silu_f(h0 * 0.125f), silu_f(h1 * 0.125f), silu_f(h2 * 0.125f), silu_f(h3 * 0.125f));
    }
    __syncthreads();
    {
      float h0 = 0.f, h1 = 0.f, h2 = 0.f, h3 = 0.f;
#pragma unroll 8
      for (int k = 0; k < 64; k++) {
        float wv = W3[k * 64 + o];
        float4 hb = *(const float4*)&hLb[k][gq * 4];
        h0 += hb.x * wv; h1 += hb.y * wv; h2 += hb.z * wv; h3 += hb.w * wv;
      }
      *(float4*)&hLa[o][gq * 4] = make_float4(
          silu_f(h0 * 0.125f), silu_f(h1 * 0.125f), silu_f(h2 * 0.125f), silu_f(h3 * 0.125f));
    }
    __syncthreads();
#pragma unroll 1
    for (int pp = 0; pp < 2; pp++) {
      const int gb = hh * 8 + pp * 4;
      float4 w4g[4];
#pragma unroll
      for (int i = 0; i < 4; i++) w4g[i] = make_float4(0.f, 0.f, 0.f, 0.f);
      {
        const float* W4p = W4 + u * 4;
#pragma unroll 4
        for (int k = 0; k < 64; k++) {
          float4 wv = *(const float4*)(W4p + k * 512);
          float4 ha = *(const float4*)&hLa[k][gb];
          w4g[0].x += ha.x * wv.x; w4g[0].y += ha.x * wv.y; w4g[0].z += ha.x * wv.z; w4g[0].w += ha.x * wv.w;
          w4g[1].x += ha.y * wv.x; w4g[1].y += ha.y * wv.y; w4g[1].z += ha.y * wv.z; w4g[1].w += ha.y * wv.w;
          w4g[2].x += ha.z * wv.x; w4g[2].y += ha.z * wv.y; w4g[2].z += ha.z * wv.z; w4g[2].w += ha.z * wv.w;
          w4g[3].x += ha.w * wv.x; w4g[3].y += ha.w * wv.y; w4g[3].z += ha.w * wv.z; w4g[3].w += ha.w * wv.w;
        }
      }
      float2 wmg[4];
#pragma unroll
      for (int i = 0; i < 4; i++) wmg[i] = make_float2(0.f, 0.f);
      {
        const float* Mcp = Mc + u * 2;
#pragma unroll 4
        for (int k = 0; k < 16; k++) {
          float2 mv = *(const float2*)(Mcp + k * 256);
          float4 ea = *(const float4*)&efL[k][gb];
          wmg[0].x += ea.x * mv.x; wmg[0].y += ea.x * mv.y;
          wmg[1].x += ea.y * mv.x; wmg[1].y += ea.y * mv.y;
          wmg[2].x += ea.z * mv.x; wmg[2].y += ea.z * mv.y;
          wmg[3].x += ea.w * mv.x; wmg[3].y += ea.w * mv.y;
        }
      }
#pragma unroll
      for (int i = 0; i < 4; i++) {
        int g = gb + i;
        int sg = __shfl(s16, g);
        float xv = x[(size_t)sg * 128 + u];
        float4 s0 = *(const float4*)&shL[g][0];
        float4 s4 = *(const float4*)&shL[g][4];
        float4 s8 = *(const float4*)&shL[g][8];
        float4 s12 = *(const float4*)&shL[g][12];
        float4 mh = *(const float4*)&mmshL[g][0];
        float w40 = w4g[i].x * 0.125f, w41 = w4g[i].y * 0.125f;
        float w42 = w4g[i].z * 0.125f, w43 = w4g[i].w * 0.125f;
        float xvp = xv;
        float pre0 = w40 * xvp * s0.x;
        float wg0 = wmg[i].x * pre0;
        float wg1 = wmg[i].y * pre0;
        float mm0 = wg0 * xvp * mh.x;
        float c = wg1 * xvp;
        float bx = mm0 * xvp;
        float a0 = w40 * bx, a1 = w41 * bx, a2 = w42 * bx, a3 = w43 * bx;
        accmm[0] += mm0;
        accmm[1] += c * mh.y;
        accmm[2] += c * mh.z;
        accmm[3] += c * mh.w;
        accm[0] += a0 * s0.x;
        accm[1] += a1 * s0.y;
        accm[2] += a1 * s0.z;
        accm[3] += a1 * s0.w;
        accm[4] += a2 * s4.x;
        accm[5] += a2 * s4.y;
        accm[6] += a2 * s4.z;
        accm[7] += a2 * s4.w;
        accm[8] += a2 * s8.x;
        accm[9] += a3 * s8.y;
        accm[10] += a3 * s8.z;
        accm[11] += a3 * s8.w;
        accm[12] += a3 * s12.x;
        accm[13] += a3 * s12.y;
        accm[14] += a3 * s12.z;
        accm[15] += a3 * s12.w;
      }
    }
    __syncthreads();
  }

#pragma unroll
  for (int m = 0; m < 16; m++) atomicAdd(&msg_s[u][m], accm[m]);
#pragma unroll
  for (int j = 0; j < 4; j++) atomicAdd(&mm_s[u][j], accmm[j]);
  if (jst == 0) atomicAdd(&dsum_s, dens_acc);
  __syncthreads();

  const int uo = t & 127;
  const int half = t >> 7;
  const float dinv = 1.0f / (dsum_s + 1.0f);

  float outl[8] = {0, 0, 0, 0, 0, 0, 0, 0};
  if (half == 0) {
    for (int uu = 0; uu < 128; uu++) {
      float wl0 = Wlin[uu * 128 + uo];
      float wl1 = Wlin[16384 + uu * 128 + uo];
      float wl2 = Wlin[32768 + uu * 128 + uo];
      outl[0] += msg_s[uu][0] * wl0;
      outl[1] += msg_s[uu][1] * wl1;
      outl[2] += msg_s[uu][2] * wl1;
      outl[3] += msg_s[uu][3] * wl1;
      outl[4] += msg_s[uu][4] * wl2;
      outl[5] += msg_s[uu][5] * wl2;
      outl[6] += msg_s[uu][6] * wl2;
      outl[7] += msg_s[uu][7] * wl2;
    }
  } else {
    for (int uu = 0; uu < 128; uu++) {
      float wl2 = Wlin[32768 + uu * 128 + uo];
      float wl3 = Wlin[49152 + uu * 128 + uo];
      outl[0] += msg_s[uu][8] * wl2;
      outl[1] += msg_s[uu][9] * wl3;
      outl[2] += msg_s[uu][10] * wl3;
      outl[3] += msg_s[uu][11] * wl3;
      outl[4] += msg_s[uu][12] * wl3;
      outl[5] += msg_s[uu][13] * wl3;
      outl[6] += msg_s[uu][14] * wl3;
      outl[7] += msg_s[uu][15] * wl3;
    }
  }
  const float scl = 0.08838834764831845f * dinv;
  float4 v0 = make_float4(outl[0] * scl, outl[1] * scl, outl[2] * scl, outl[3] * scl);
  float4 v1 = make_float4(outl[4] * scl, outl[5] * scl, outl[6] * scl, outl[7] * scl);
  float4* lp = (float4*)(linm + (size_t)n * 2048 + uo * 16 + half * 8);
  lp[0] = v0;
  lp[1] = v1;

  float om0 = 0.f, om1 = 0.f;
  if (half == 0) {
    for (int uu = 0; uu < 128; uu++) {
      om0 += mm_s[uu][0] * Wmlin[uu * 128 + uo];
      om1 += mm_s[uu][1] * Wmlin[16384 + uu * 128 + uo];
    }
  } else {
    for (int uu = 0; uu < 128; uu++) {
      float wm1 = Wmlin[16384 + uu * 128 + uo];
      om0 += mm_s[uu][2] * wm1;
      om1 += mm_s[uu][3] * wm1;
    }
  }
  const float sm = 0.08838834764831845f / 20.0f;
  *(float2*)(linmm + (size_t)n * 512 + uo * 4 + half * 2) = make_float2(om0 * sm, om1 * sm);
}

// zero out2 blocks l=2,3 (no path -> zero)
__global__ void k_zero2(float* __restrict__ out2, int Nn) {
  int i = blockIdx.x * blockDim.x + threadIdx.x;
  if (i < Nn * 128) {
    float4 z = make_float4(0.f, 0.f, 0.f, 0.f);
    float4* p = (float4*)(out2 + (size_t)i * 16);
    p[1] = z;
    p[2] = z;
    p[3] = z;
  }
}

// ---------------- skip tensor product (barrier-free inner loop) ----------
__global__ __launch_bounds__(128) void k_wt(const float* __restrict__ Wskip,
                                            const float* __restrict__ Wmskip,
                                            float* __restrict__ Wt) {
  int bx = blockIdx.x;
  int L = bx >> 7, u = bx & 127;
  int v = threadIdx.x;
  const float* src = (L < 4) ? (Wskip + (size_t)L * 163840)
                             : (Wmskip + (size_t)(L - 4) * 163840);
  float* dst = Wt + (((size_t)L * 128 + u) * 128 + v) * 12;
#pragma unroll
  for (int z = 0; z < 10; z++) dst[z] = src[u * 1280 + z * 128 + v];
  dst[10] = 0.f;
  dst[11] = 0.f;
}

template <int D, int SP>
__device__ __forceinline__ void skip_body2(
    const float* __restrict__ attrs, const float* __restrict__ in, int in_rs,
    int in_us, int in_cb, const float* __restrict__ Wt, float* __restrict__ outp,
    int out_cb, int Nn, int n0, float* lin_s, float (*attrs_s)[10]) {
  const int t = threadIdx.x;
  for (int i = t; i < 160; i += 256) {
    int nn = i / 10, z = i - nn * 10;
    int n = n0 + nn;
    attrs_s[nn][z] = (n < Nn) ? attrs[n * 10 + z] : 0.f;
  }
  for (int i = t; i < 16 * 128 * D; i += 256) {
    int nn = i / (128 * D);
    int r = i - nn * 128 * D;
    int uu = r / D;
    int m = r - uu * D;
    int n = n0 + nn;
    lin_s[(nn * 128 + uu) * SP + m] =
        (n < Nn) ? in[(size_t)n * in_rs + uu * in_us + in_cb + m] : 0.f;
  }
  __syncthreads();

  const int v = t & 127, hf = t >> 7;
  float ar[8][10];
#pragma unroll
  for (int q = 0; q < 8; q++)
#pragma unroll
    for (int z = 0; z < 10; z++) ar[q][z] = attrs_s[hf * 8 + q][z];

  float acc[8][D];
#pragma unroll
  for (int q = 0; q < 8; q++)
#pragma unroll
    for (int m = 0; m < D; m++) acc[q][m] = 0.f;

  const float* wp0 = Wt + (size_t)v * 12;
  for (int u = 0; u < 128; u++) {
    const float* wp = wp0 + (size_t)u * 1536;
    float4 wa = *(const float4*)wp;
    float4 wb = *(const float4*)(wp + 4);
    float2 wc = *(const float2*)(wp + 8);
    float wr[10] = {wa.x, wa.y, wa.z, wa.w, wb.x, wb.y, wb.z, wb.w, wc.x, wc.y};
#pragma unroll
    for (int q = 0; q < 8; q++) {
      float wn = 0.f;
#pragma unroll
      for (int z = 0; z < 10; z++) wn += ar[q][z] * wr[z];
      const float* ls = &lin_s[((hf * 8 + q) * 128 + u) * SP];
#pragma unroll
      for (int m = 0; m < D; m++) acc[q][m] += ls[m] * wn;
    }
  }
#pragma unroll
  for (int q = 0; q < 8; q++) {
    int n = n0 + hf * 8 + q;
    if (n < Nn) {
      float* op = outp + (size_t)n * 2048 + v * 16 + out_cb;
#pragma unroll
      for (int m = 0; m < D; m++) op[m] = acc[q][m] * 0.027950849718747371f;
    }
  }
}

__global__ __launch_bounds__(256) void k_skip(
    const float* __restrict__ attrs, const float* __restrict__ linm,
    const float* __restrict__ linmm, const float* __restrict__ Wt,
    float* __restrict__ out, int Nn) {
  __shared__ float lin_s[16 * 128 * 8];
  __shared__ float attrs_s[16][10];
  const int n0 = blockIdx.x * 16;
  const int job = blockIdx.y;
  const float* Wtj = Wt + (size_t)job * 128 * 128 * 12;
  switch (job) {
    case 0: skip_body2<1, 1>(attrs, linm, 2048, 16, 0, Wtj, out, 0, Nn, n0, lin_s, attrs_s); break;
    case 1: skip_body2<3, 4>(attrs, linm, 2048, 16, 1, Wtj, out, 1, Nn, n0, lin_s, attrs_s); break;
    case 2: skip_body2<5, 8>(attrs, linm, 2048, 16, 4, Wtj, out, 4, Nn, n0, lin_s, attrs_s); break;
    case 3: skip_body2<7, 8>(attrs, linm, 2048, 16, 9, Wtj, out, 9, Nn, n0, lin_s, attrs_s); break;
    case 4: skip_body2<1, 1>(attrs, linmm, 512, 4, 0, Wtj, out + (size_t)Nn * 2048, 0, Nn, n0, lin_s, attrs_s); break;
    case 5: skip_body2<3, 4>(attrs, linmm, 512, 4, 1, Wtj, out + (size_t)Nn * 2048, 1, Nn, n0, lin_s, attrs_s); break;
  }
}

extern "C" void kernel_launch(void* const* d_in, const int* in_sizes, int n_in,
                              void* d_out, int out_size, void* d_ws, size_t ws_size,
                              hipStream_t stream) {
  const float* node_attrs = (const float*)d_in[0];
  const float* node_feats = (const float*)d_in[1];
  const float* edge_attrs = (const float*)d_in[2];
  const float* edge_feats = (const float*)d_in[3];
  const float* mminv = (const float*)d_in[4];
  const float* mmattrs = (const float*)d_in[5];
  const int* edge_index = (const int*)d_in[6];
  const float* W_up = (const float*)d_in[7];
  const float* W1 = (const float*)d_in[8];
  const float* W2 = (const float*)d_in[9];
  const float* W3 = (const float*)d_in[10];
  const float* W4 = (const float*)d_in[11];
  const float* M1 = (const float*)d_in[12];
  const float* M2 = (const float*)d_in[13];
  const float* M3 = (const float*)d_in[14];
  const float* M4 = (const float*)d_in[15];
  const float* Wd = (const float*)d_in[16];
  const float* Wlin = (const float*)d_in[17];
  const float* Wmlin = (const float*)d_in[18];
  const float* Wskip = (const float*)d_in[19];
  const float* Wmskip = (const float*)d_in[20];

  const int N = in_sizes[1] / 128;
  const int E = in_sizes[2] / 16;
  const int* sender = edge_index;
  const int* recv = edge_index + E;

  float* ws = (float*)d_ws;
  float* x = ws;        ws += (size_t)N * 128;
  float* Mc = ws;       ws += 16 * 256;
  float* linm = ws;     ws += (size_t)N * 2048;
  float* linmm = ws;    ws += (size_t)N * 512;
  float* Wt = ws;       ws += (size_t)6 * 128 * 128 * 12;
  float* dens = ws;     ws += (size_t)((E + 3) / 4) * 4;
  int* ibuf = (int*)ws;
  int* rowstart = ibuf;            // N+1
  int* deg = ibuf + (N + 1);       // N
  int* cursor = deg + N;           // N
  int* elist = cursor + N;         // E
  // w4out, 16B-aligned, after the int buffers
  size_t int_words = (size_t)(3 * N + 1 + E);
  size_t off_w4 = ((((char*)(ibuf + int_words)) - (char*)d_ws) + 15) & ~(size_t)15;
  float* w4out = (float*)((char*)d_ws + off_w4);
  size_t need = off_w4 + (size_t)E * 512 * 4;
  const bool split = (ws_size >= need);

  k_zero_int<<<(N + 255) / 256, 256, 0, stream>>>(deg, N);
  k_prep<<<1, 256, 0, stream>>>(M1, M2, M3, M4, Mc);
  k_wt<<<768, 128, 0, stream>>>(Wskip, Wmskip, Wt);
  k_up<<<N, 128, 0, stream>>>(node_feats, W_up, x, N);
  k_count<<<(E + 255) / 256, 256, 0, stream>>>(recv, deg, E);
  k_scan<<<1, 1024, 0, stream>>>(deg, rowstart, cursor, N);
  k_fill<<<(E + 255) / 256, 256, 0, stream>>>(recv, cursor, elist, E);
  if (split) {
    k_mlp<<<(E + 31) / 32, 256, 0, stream>>>(edge_feats, mminv, sender, W1, W2,
                                             W3, W4, Wd, w4out, dens, E);
    k_gate<<<N, 256, 0, stream>>>(x, edge_attrs, edge_feats, mminv, mmattrs,
                                  sender, Mc, w4out, dens, Wlin, Wmlin,
                                  rowstart, elist, linm, linmm, N);
  } else {
    k_gather<<<N, 256, 0, stream>>>(x, edge_attrs, edge_feats, mminv, mmattrs,
                                    sender, W1, W2, W3, W4, Mc, Wd, Wlin, Wmlin,
                                    rowstart, elist, linm, linmm, N);
  }
  k_zero2<<<(N * 128 + 255) / 256, 256, 0, stream>>>((float*)d_out + (size_t)N * 2048, N);
  dim3 gs((N + 15) / 16, 6);
  k_skip<<<gs, 256, 0, stream>>>(node_attrs, linm, linmm, Wt, (float*)d_out, N);
}